// Round 1
// baseline (2722.603 us; speedup 1.0000x reference)
//
#include <hip/hip_runtime.h>
#include <math.h>

// Problem constants (from reference)
#define BATCH   4096
#define NPUMP   4
#define NCH     100
#define NTOT    104          // NPUMP + NCH
#define RESPLEN 801
#define NSTEPS  499          // STEPS - 1

// dz = 50000/499 computed in double, rounded to float (matches jax scalar folding)
#define DZ_F   100.20040080160321f
#define HDZ_F  50.100200400801604f   // 0.5*dz
#define DZ6_F  16.700066800267202f   // dz/6

__device__ __forceinline__ float gentry(float fi, float fj, const float* __restrict__ resp_s)
{
    // D[i][j] = f_j - f_i ; ratio[i][j] = f_i / f_j
    float D    = fj - fi;
    float ad   = fabsf(D);
    float fidx = ad / 5.0e10f;          // DF = FS/N_SAMP = 5e10
    int   i0   = (int)fidx;             // floor (fidx >= 0)
    i0 = i0 > (RESPLEN - 2) ? (RESPLEN - 2) : i0;
    float w  = fidx - (float)i0;
    float g  = resp_s[i0] * (1.0f - w) + resp_s[i0 + 1] * w;
    g = (D < 0.0f) ? -g : g;
    float ratio = fi / fj;
    float m  = fmaxf(1.0f, ratio);
    return g * m / 8e-11f;              // / EFFECTIVE_AREA
}

__global__ __launch_bounds__(64) void raman_kernel(
    const float* __restrict__ x,        // (BATCH, 8): [wl0..wl3, pw0..pw3]
    const float* __restrict__ resp,     // (801,)
    const float* __restrict__ sigwl,    // (100,)
    float* __restrict__ out)            // (BATCH, 100)
{
    const int b    = blockIdx.x;
    const int lane = threadIdx.x;       // 0..63, one wave per block

    __shared__ float resp_s[RESPLEN];
    __shared__ __align__(16) float fr_s[NTOT];
    __shared__ __align__(16) float Pb[2][NTOT];

    // stage raman response into LDS
    for (int i = lane; i < RESPLEN; i += 64) resp_s[i] = resp[i];

    const float* xb = x + b * 8;

    // rows handled by this lane
    const int  r0 = lane;
    const int  r1 = 64 + lane;
    const bool a1 = (r1 < NTOT);

    // frequencies into LDS (f32, matching ref: C0 / lambda)
    {
        float lam0 = (r0 < NPUMP) ? xb[r0] : sigwl[r0 - NPUMP];
        fr_s[r0] = 299792458.0f / lam0;
        if (a1) {
            float lam1 = sigwl[r1 - NPUMP];
            fr_s[r1] = 299792458.0f / lam1;
        }
    }
    __syncthreads();

    // losses: (C2 + C1*lam + C0*lam^2)*ln10/10 with C0=C1=0 -> constant
    const float loss = 0.0002f * 0.23025850929940458f;

    // initial powers: pumps relu(abs(pw)) = abs(pw); signals 1e-3
    float p0 = (r0 < NPUMP) ? fabsf(xb[NPUMP + r0]) : 0.001f;
    float p1 = a1 ? 0.001f : 0.0f;

    // ---- build G rows into registers (26 float4 per row) ----
    float4 G0[26], G1[26];
    const float fi0 = fr_s[r0];
    const float fi1 = a1 ? fr_s[r1] : 1.0f;   // dummy for inactive (p1=0 kills it)
    #pragma unroll
    for (int jj = 0; jj < 26; ++jj) {
        float4 fj = ((const float4*)fr_s)[jj];
        G0[jj].x = gentry(fi0, fj.x, resp_s);
        G0[jj].y = gentry(fi0, fj.y, resp_s);
        G0[jj].z = gentry(fi0, fj.z, resp_s);
        G0[jj].w = gentry(fi0, fj.w, resp_s);
        G1[jj].x = gentry(fi1, fj.x, resp_s);
        G1[jj].y = gentry(fi1, fj.y, resp_s);
        G1[jj].z = gentry(fi1, fj.z, resp_s);
        G1[jj].w = gentry(fi1, fj.w, resp_s);
    }

    // ---- RK4 main loop ----
    // stage: write stage powers to Pb[buf], read back full vector, two dots
    auto stage = [&](float ps0, float ps1, int buf, float& k0, float& k1r) {
        Pb[buf][r0] = ps0;
        if (a1) Pb[buf][r1] = ps1;
        __syncthreads();
        float a00 = 0.f, a01 = 0.f, a10 = 0.f, a11 = 0.f;
        const float4* pv4 = (const float4*)Pb[buf];
        #pragma unroll
        for (int jj = 0; jj < 26; ++jj) {
            float4 pv = pv4[jj];
            a00 = fmaf(G0[jj].x, pv.x, a00);
            a01 = fmaf(G0[jj].y, pv.y, a01);
            a00 = fmaf(G0[jj].z, pv.z, a00);
            a01 = fmaf(G0[jj].w, pv.w, a01);
            a10 = fmaf(G1[jj].x, pv.x, a10);
            a11 = fmaf(G1[jj].y, pv.y, a11);
            a10 = fmaf(G1[jj].z, pv.z, a10);
            a11 = fmaf(G1[jj].w, pv.w, a11);
        }
        k0  = ((a00 + a01) - loss) * ps0;
        k1r = ((a10 + a11) - loss) * ps1;
    };

    for (int s = 0; s < NSTEPS; ++s) {
        float k1a, k1b, k2a, k2b, k3a, k3b, k4a, k4b;
        stage(p0, p1, 0, k1a, k1b);
        stage(p0 + HDZ_F * k1a, p1 + HDZ_F * k1b, 1, k2a, k2b);
        stage(p0 + HDZ_F * k2a, p1 + HDZ_F * k2b, 0, k3a, k3b);
        stage(p0 + DZ_F  * k3a, p1 + DZ_F  * k3b, 1, k4a, k4b);
        p0 = p0 + DZ6_F * (k1a + 2.0f * k2a + 2.0f * k3a + k4a);
        p1 = p1 + DZ6_F * (k1b + 2.0f * k2b + 2.0f * k3b + k4b);
    }

    // ---- output: rows NPUMP..NTOT-1 -> (BATCH, 100) ----
    float* outb = out + b * NCH;
    if (r0 >= NPUMP) outb[r0 - NPUMP] = p0;
    if (a1)          outb[r1 - NPUMP] = p1;
}

extern "C" void kernel_launch(void* const* d_in, const int* in_sizes, int n_in,
                              void* d_out, int out_size, void* d_ws, size_t ws_size,
                              hipStream_t stream)
{
    const float* x     = (const float*)d_in[0];
    const float* resp  = (const float*)d_in[1];
    const float* sigwl = (const float*)d_in[2];
    float* out = (float*)d_out;
    raman_kernel<<<BATCH, 64, 0, stream>>>(x, resp, sigwl, out);
}